// Round 7
// baseline (556.762 us; speedup 1.0000x reference)
//
#include <hip/hip_runtime.h>
#include <hip/hip_bf16.h>
#include <stdint.h>

// Problem dims
#define BATCH 256
#define SEQ   512
#define INDIM 64
#define H     128
#define RB    4               // batch rows per block (valid C-rows at quad*4, r=0)
#define NTILE (BATCH / RB)    // 64 batch tiles per layer
#define CH    16              // pipeline handoff chunk (steps)
#define NCH   (SEQ / CH)

using short8  = __attribute__((ext_vector_type(8))) short;  // 8 bf16 MFMA A/B frag
using float4v = __attribute__((ext_vector_type(4))) float;  // MFMA C/D frag

#define LOG2E 1.4426950408889634f

__device__ __forceinline__ unsigned short f2bf(float f) {
    union { float f; uint32_t u; } v; v.f = f;
    uint32_t u = v.u;
    return (unsigned short)((u + 0x7FFFu + ((u >> 16) & 1u)) >> 16); // RNE
}

__device__ __forceinline__ float fast_exp2(float x) {
#if __has_builtin(__builtin_amdgcn_exp2f)
    return __builtin_amdgcn_exp2f(x);
#else
    return __expf(x * 0.6931471805599453f);
#endif
}
__device__ __forceinline__ float fast_rcp(float x) {
#if __has_builtin(__builtin_amdgcn_rcpf)
    return __builtin_amdgcn_rcpf(x);
#else
    return 1.f / x;
#endif
}
__device__ __forceinline__ float sigmoid_fast(float x) {
    return fast_rcp(1.f + fast_exp2(-LOG2E * x));
}
__device__ __forceinline__ float tanh_fast(float x) {
    return fmaf(-2.f, fast_rcp(1.f + fast_exp2((2.f * LOG2E) * x)), 1.f);
}

// In-step barrier: LDS ordering only (lgkmcnt). Global prefetch loads and
// producer h-stores stay in flight across it. Full __syncthreads (vmcnt
// drain) only at chunk boundaries.
__device__ __forceinline__ void light_barrier() {
    asm volatile("s_waitcnt lgkmcnt(0)\n\ts_barrier" ::: "memory");
}

// ---------------- x fp32 -> bf16 convert (+ flag zeroing) ----------------
__global__ void conv_x_kernel(const float* __restrict__ x,
                              unsigned short* __restrict__ xb, int n4,
                              int* __restrict__ flags) {
    int i = blockIdx.x * blockDim.x + threadIdx.x;
    if (blockIdx.x == 0 && threadIdx.x < NTILE) flags[threadIdx.x] = 0;
    if (i >= n4) return;
    float4 f = ((const float4*)x)[i];
    ushort4 o;
    o.x = f2bf(f.x); o.y = f2bf(f.y); o.z = f2bf(f.z); o.w = f2bf(f.w);
    ((ushort4*)xb)[i] = o;
}

// ---------------- fused 2-layer pipelined LSTM + head ----------------
// 128 blocks x 256 threads (R7: WIDE-WAVE redesign of the R3/R5 skeleton).
// Blocks 0..63: layer0 (producer), 64..127: layer1 (consumer), paired on
// batch tile bt via chunked flag handoff through global h0sq (R5 chunk
// structure kept verbatim: 1-chunk lag, thread0 poll, per-chunk refill).
//
// Established constraints/history:
//  - R0-R6: 8 thin waves (16 cells each) at 2 waves/SIMD plateau at
//    407-440us; per-wave issue ~470cy of a ~1700cy step; the rest is raw
//    latency (ds_read, MFMA dep, activation chain) that phase-locked waves
//    cannot fill. Micro-surgery on the chain is exhausted (R3 -8%; R5, R6
//    neutral/regress).
//  - R1: doubling per-wave STATE (2 batch tiles) at fixed 256-reg budget ->
//    register cliff. R2: >2 waves/SIMD -> catastrophic spill.
//
// R7 mechanism: 4 WIDE waves, 32 cells each (two 16-cell col-groups), at
// 1 wave/SIMD via __launch_bounds__(256,1) -> 512-reg budget/wave. Weights
// double (consumer: 256 VGPR) but the budget doubles too. Per-step per-wave
// issue: 64 MFMAs (~310cy) as 4 parallel depth-2 chains + 2 independent
// activation chains (ILP-2) -> the latency windows are filled with the work
// that previously ran on the other phase-locked waves. Estimated consumer
// peak live set ~400-430 < 450 no-spill line (m08).
//  - A-operands (x frag, h frag) are SHARED between col-groups; only B
//    (weights) and accumulators double.
//  - Spill tripwire: FETCH_SIZE > 40MB or dur >> 500us -> revert to R5.
// R5 lesson (still enforced): every per-thread register array is indexed
// ONLY with compile-time constants; x double buffer statically named.
template<int KIN, bool IS_PROD>
__device__ __forceinline__ void lstm_body(
    const unsigned short* __restrict__ xin,  // [BATCH][SEQ][KIN] bf16
    const float* __restrict__ Wih,           // [4H][KIN]
    const float* __restrict__ Whh,           // [4H][H]
    const float* __restrict__ b_ih, const float* __restrict__ b_hh,
    unsigned short* __restrict__ outseq,     // producer: [BATCH][SEQ][H] bf16
    const float* __restrict__ W1, const float* __restrict__ b1,
    const float* __restrict__ W2, const float* __restrict__ b2,
    float* __restrict__ out,                 // consumer: [BATCH][3]
    int* flag, int bt)
{
    constexpr int KT  = KIN / 32;
    constexpr int PAD = 132;                 // 66 dwords == 2 mod 32 -> 2-way (free) aliasing
    const int lane = threadIdx.x & 63;
    const int quad = lane >> 4;
    const int l16  = lane & 15;
    const int b0   = bt * RB;
    const int cell = (threadIdx.x >> 6) * 32 + l16;   // col-group 0 cell; group 1 = cell+16
    const int arow = l16 & 12;               // LDS h row this lane reads (4-lane broadcast)
    const int xrow = b0 + (l16 >> 2);        // batch row this lane loads (duplicated 4x)

    __shared__ short hbuf[2][16][PAD];
    __shared__ float hl[RB][128];            // fp32 h_last (consumer head input)
    __shared__ float mid[RB][65];
    for (int i = threadIdx.x; i < 2 * 16 * PAD; i += 256) ((short*)hbuf)[i] = 0;

    // ---- weight fragments (loaded once, fp32->bf16, persist in registers).
    //      Two col-groups per wave: _f = cells [cell], _g = cells [cell+16].
    short8 whh_f[4][4], whh_g[4][4];
    short8 wih_f[4][KT], wih_g[4][KT];
    float  biasA[4], biasB[4];
#pragma unroll
    for (int tT = 0; tT < 4; tT++) {
        const int n0 = tT * 128 + cell;
        const int n1 = n0 + 16;
#pragma unroll
        for (int kt = 0; kt < 4; kt++) {
            const float* p0 = Whh + (size_t)n0 * H + kt * 32 + quad * 8;
            const float* p1 = Whh + (size_t)n1 * H + kt * 32 + quad * 8;
            float4 a0 = *(const float4*)p0, a1 = *(const float4*)(p0 + 4);
            float4 c0v = *(const float4*)p1, c1v = *(const float4*)(p1 + 4);
            short8 s0, s1;
            s0[0]=f2bf(a0.x); s0[1]=f2bf(a0.y); s0[2]=f2bf(a0.z); s0[3]=f2bf(a0.w);
            s0[4]=f2bf(a1.x); s0[5]=f2bf(a1.y); s0[6]=f2bf(a1.z); s0[7]=f2bf(a1.w);
            s1[0]=f2bf(c0v.x); s1[1]=f2bf(c0v.y); s1[2]=f2bf(c0v.z); s1[3]=f2bf(c0v.w);
            s1[4]=f2bf(c1v.x); s1[5]=f2bf(c1v.y); s1[6]=f2bf(c1v.z); s1[7]=f2bf(c1v.w);
            whh_f[tT][kt] = s0;
            whh_g[tT][kt] = s1;
        }
#pragma unroll
        for (int kt = 0; kt < KT; kt++) {
            const float* p0 = Wih + (size_t)n0 * KIN + kt * 32 + quad * 8;
            const float* p1 = Wih + (size_t)n1 * KIN + kt * 32 + quad * 8;
            float4 a0 = *(const float4*)p0, a1 = *(const float4*)(p0 + 4);
            float4 c0v = *(const float4*)p1, c1v = *(const float4*)(p1 + 4);
            short8 s0, s1;
            s0[0]=f2bf(a0.x); s0[1]=f2bf(a0.y); s0[2]=f2bf(a0.z); s0[3]=f2bf(a0.w);
            s0[4]=f2bf(a1.x); s0[5]=f2bf(a1.y); s0[6]=f2bf(a1.z); s0[7]=f2bf(a1.w);
            s1[0]=f2bf(c0v.x); s1[1]=f2bf(c0v.y); s1[2]=f2bf(c0v.z); s1[3]=f2bf(c0v.w);
            s1[4]=f2bf(c1v.x); s1[5]=f2bf(c1v.y); s1[6]=f2bf(c1v.z); s1[7]=f2bf(c1v.w);
            wih_f[tT][kt] = s0;
            wih_g[tT][kt] = s1;
        }
        biasA[tT] = b_ih[n0] + b_hh[n0];
        biasB[tT] = b_ih[n1] + b_hh[n1];
    }

    float cs0 = 0.f, cs1 = 0.f;              // cell states: col-groups 0 and 1

    const unsigned short* xp = xin + ((size_t)xrow * SEQ) * KIN + quad * 8;
    unsigned short* op = nullptr;
    if (IS_PROD)
        op = outseq + ((size_t)(b0 + quad) * SEQ) * H + cell;

    short8 xf0[KT], xf1[KT];                 // statically-named x double buffer
    __syncthreads();                         // hbuf zero-init visible

    // One step. Consumes xf (= x(t)); reloads xf = x(t+2) right after the
    // x-MFMAs (dist-2, R4 lesson). Per col-group gate math (R3 structure):
    //   accA = bias + x0 + x1 [+ x2 + x3 folded into A] + h0 + h1
    //   accB = [x2 + x3 +] h2 + h3
    //   g = accA[0] + accB[0]
    // 4 gate-tiles x 2 groups x 2 chains = 16 parallel acc quads.
    auto step = [&](int t, int CUR, short8 (&xf)[KT],
                    bool doPre) __attribute__((always_inline)) {
        short8 ha[4];
#pragma unroll
        for (int kt = 0; kt < 4; kt++)
            ha[kt] = *(const short8*)&hbuf[CUR][arow][kt * 32 + quad * 8];

        float4v aA0[4], aB0[4], aA1[4], aB1[4];  // in-step only
#pragma unroll
        for (int tT = 0; tT < 4; tT++) {
            aA0[tT] = (float4v){biasA[tT], biasA[tT], biasA[tT], biasA[tT]};
            aA1[tT] = (float4v){biasB[tT], biasB[tT], biasB[tT], biasB[tT]};
            aB0[tT] = (float4v){0.f, 0.f, 0.f, 0.f};
            aB1[tT] = (float4v){0.f, 0.f, 0.f, 0.f};
        }
        // x-projection from prefetched regs (fills the ds_read latency window)
#pragma unroll
        for (int tT = 0; tT < 4; tT++) {
            aA0[tT] = __builtin_amdgcn_mfma_f32_16x16x32_bf16(xf[0], wih_f[tT][0], aA0[tT], 0, 0, 0);
            aA1[tT] = __builtin_amdgcn_mfma_f32_16x16x32_bf16(xf[0], wih_g[tT][0], aA1[tT], 0, 0, 0);
        }
#pragma unroll
        for (int tT = 0; tT < 4; tT++) {
            aA0[tT] = __builtin_amdgcn_mfma_f32_16x16x32_bf16(xf[1], wih_f[tT][1], aA0[tT], 0, 0, 0);
            aA1[tT] = __builtin_amdgcn_mfma_f32_16x16x32_bf16(xf[1], wih_g[tT][1], aA1[tT], 0, 0, 0);
        }
        if constexpr (KT == 4) {
#pragma unroll
            for (int tT = 0; tT < 4; tT++) {
                aB0[tT] = __builtin_amdgcn_mfma_f32_16x16x32_bf16(xf[2], wih_f[tT][2], aB0[tT], 0, 0, 0);
                aB1[tT] = __builtin_amdgcn_mfma_f32_16x16x32_bf16(xf[2], wih_g[tT][2], aB1[tT], 0, 0, 0);
            }
#pragma unroll
            for (int tT = 0; tT < 4; tT++) {
                aB0[tT] = __builtin_amdgcn_mfma_f32_16x16x32_bf16(xf[3], wih_f[tT][3], aB0[tT], 0, 0, 0);
                aB1[tT] = __builtin_amdgcn_mfma_f32_16x16x32_bf16(xf[3], wih_g[tT][3], aB1[tT], 0, 0, 0);
            }
        }
        if (doPre) {                         // reload xf = x(t+2) (WAR after use)
            const unsigned short* p = xp + (size_t)(t + 2) * KIN;
#pragma unroll
            for (int kt = 0; kt < KT; kt++) xf[kt] = *(const short8*)(p + kt * 32);
        }
        // recurrent projection: 8 parallel depth-2 chains (4 per col-group)
#pragma unroll
        for (int tT = 0; tT < 4; tT++) {
            aA0[tT] = __builtin_amdgcn_mfma_f32_16x16x32_bf16(ha[0], whh_f[tT][0], aA0[tT], 0, 0, 0);
            aA1[tT] = __builtin_amdgcn_mfma_f32_16x16x32_bf16(ha[0], whh_g[tT][0], aA1[tT], 0, 0, 0);
        }
#pragma unroll
        for (int tT = 0; tT < 4; tT++) {
            aB0[tT] = __builtin_amdgcn_mfma_f32_16x16x32_bf16(ha[2], whh_f[tT][2], aB0[tT], 0, 0, 0);
            aB1[tT] = __builtin_amdgcn_mfma_f32_16x16x32_bf16(ha[2], whh_g[tT][2], aB1[tT], 0, 0, 0);
        }
#pragma unroll
        for (int tT = 0; tT < 4; tT++) {
            aA0[tT] = __builtin_amdgcn_mfma_f32_16x16x32_bf16(ha[1], whh_f[tT][1], aA0[tT], 0, 0, 0);
            aA1[tT] = __builtin_amdgcn_mfma_f32_16x16x32_bf16(ha[1], whh_g[tT][1], aA1[tT], 0, 0, 0);
        }
#pragma unroll
        for (int tT = 0; tT < 4; tT++) {
            aB0[tT] = __builtin_amdgcn_mfma_f32_16x16x32_bf16(ha[3], whh_f[tT][3], aB0[tT], 0, 0, 0);
            aB1[tT] = __builtin_amdgcn_mfma_f32_16x16x32_bf16(ha[3], whh_g[tT][3], aB1[tT], 0, 0, 0);
        }

        // ---- col-group 0 ----
        float g00 = aA0[0][0] + aB0[0][0];
        float g01 = aA0[1][0] + aB0[1][0];
        float g02 = aA0[2][0] + aB0[2][0];
        float g03 = aA0[3][0] + aB0[3][0];
        // ---- col-group 1 ----
        float g10 = aA1[0][0] + aB1[0][0];
        float g11 = aA1[1][0] + aB1[1][0];
        float g12 = aA1[2][0] + aB1[2][0];
        float g13 = aA1[3][0] + aB1[3][0];

        // two independent activation chains (ILP-2)
        float si0 = sigmoid_fast(g00), si1 = sigmoid_fast(g10);
        float sf0 = sigmoid_fast(g01), sf1 = sigmoid_fast(g11);
        float tg0 = tanh_fast(g02),    tg1 = tanh_fast(g12);
        float so0 = sigmoid_fast(g03), so1 = sigmoid_fast(g13);
        cs0 = fmaf(sf0, cs0, si0 * tg0);
        cs1 = fmaf(sf1, cs1, si1 * tg1);
        float h0 = so0 * tanh_fast(cs0);
        float h1 = so1 * tanh_fast(cs1);
        uint32_t hp;                          // pack both cells, single RNE cvt
        asm("v_cvt_pk_bf16_f32 %0, %1, %2" : "=v"(hp) : "v"(h0), "v"(h1));
        const unsigned short lo = (unsigned short)(hp & 0xffffu);
        const unsigned short hi = (unsigned short)(hp >> 16);
        hbuf[CUR ^ 1][quad * 4][cell]      = (short)lo;
        hbuf[CUR ^ 1][quad * 4][cell + 16] = (short)hi;
        if (IS_PROD) {
            op[0]  = lo;                      // fire-and-forget; drained at chunk end
            op[16] = hi;
            op += H;
        } else if (t == SEQ - 1) {
            hl[quad][cell]      = h0;
            hl[quad][cell + 16] = h1;
        }
        light_barrier();                     // LDS-only: loads/stores stay in flight
    };

    for (int ch = 0; ch < NCH; ch++) {
        const int t0 = ch * CH;
        if (!IS_PROD) {
            if (threadIdx.x == 0) {
                while (__hip_atomic_load(flag, __ATOMIC_RELAXED, __HIP_MEMORY_SCOPE_AGENT) <= ch)
                    __builtin_amdgcn_s_sleep(2);
                (void)__hip_atomic_load(flag, __ATOMIC_ACQUIRE, __HIP_MEMORY_SCOPE_AGENT);
            }
            __syncthreads();
        }
        // chunk fill: consumer every chunk (x not readable across the flag);
        // producer only once (its depth-2 reload pipeline runs across chunks)
        if (!IS_PROD || ch == 0) {
            const unsigned short* p0 = xp + (size_t)t0 * KIN;
            const unsigned short* p1 = p0 + KIN;
#pragma unroll
            for (int kt = 0; kt < KT; kt++) {
                xf0[kt] = *(const short8*)(p0 + kt * 32);
                xf1[kt] = *(const short8*)(p1 + kt * 32);
            }
        }

#pragma unroll 1
        for (int i = 0; i < CH; i += 2) {
            const int t = t0 + i;
            const bool pre0 = IS_PROD ? (t + 2 < SEQ) : (i + 2 < CH);
            const bool pre1 = IS_PROD ? (t + 3 < SEQ) : (i + 3 < CH);
            step(t,     0, xf0, pre0);       // even -> reads hbuf[0], writes hbuf[1]
            step(t + 1, 1, xf1, pre1);       // odd  -> reads hbuf[1], writes hbuf[0]
        }
        __syncthreads();                     // vmcnt drain (producer stores) + boundary
        if (IS_PROD && threadIdx.x == 0)
            __hip_atomic_fetch_add(flag, 1, __ATOMIC_RELEASE, __HIP_MEMORY_SCOPE_AGENT);
    }

    if (!IS_PROD) {
        // ---- MLP head for this block's RB rows (hl visible via last barrier)
        {
            const int row = threadIdx.x >> 6, j = threadIdx.x & 63;
            float s = b1[j];
            const float* wr = W1 + (size_t)j * 128;
#pragma unroll 8
            for (int k = 0; k < 128; k++) s = fmaf(hl[row][k], wr[k], s);
            mid[row][j] = fmaxf(s, 0.f);
        }
        __syncthreads();
        if (threadIdx.x < RB * 3) {
            const int row = threadIdx.x / 3, k = threadIdx.x - row * 3;
            float o = b2[k];
            const float* wr = W2 + (size_t)k * 64;
#pragma unroll 8
            for (int j = 0; j < 64; j++) o = fmaf(mid[row][j], wr[j], o);
            out[(size_t)(b0 + row) * 3 + k] = o;
        }
    }
}

__global__ __launch_bounds__(256, 1)
void lstm_fused_kernel(const unsigned short* __restrict__ xb,
                       const float* __restrict__ Wih0, const float* __restrict__ Whh0,
                       const float* __restrict__ bih0, const float* __restrict__ bhh0,
                       const float* __restrict__ Wih1, const float* __restrict__ Whh1,
                       const float* __restrict__ bih1, const float* __restrict__ bhh1,
                       unsigned short* __restrict__ h0sq,
                       const float* __restrict__ W1, const float* __restrict__ b1,
                       const float* __restrict__ W2, const float* __restrict__ b2,
                       float* __restrict__ out,
                       int* __restrict__ flags)
{
    const int bt = blockIdx.x & (NTILE - 1);
    if (blockIdx.x < NTILE)
        lstm_body<64,  true >(xb,   Wih0, Whh0, bih0, bhh0, h0sq,
                              W1, b1, W2, b2, out, flags + bt, bt);
    else
        lstm_body<128, false>(h0sq, Wih1, Whh1, bih1, bhh1, nullptr,
                              W1, b1, W2, b2, out, flags + bt, bt);
}

extern "C" void kernel_launch(void* const* d_in, const int* in_sizes, int n_in,
                              void* d_out, int out_size, void* d_ws, size_t ws_size,
                              hipStream_t stream) {
    const float* x     = (const float*)d_in[0];
    const float* W_ih0 = (const float*)d_in[1];
    const float* W_hh0 = (const float*)d_in[2];
    const float* b_ih0 = (const float*)d_in[3];
    const float* b_hh0 = (const float*)d_in[4];
    const float* W_ih1 = (const float*)d_in[5];
    const float* W_hh1 = (const float*)d_in[6];
    const float* b_ih1 = (const float*)d_in[7];
    const float* b_hh1 = (const float*)d_in[8];
    const float* W1    = (const float*)d_in[9];
    const float* b1    = (const float*)d_in[10];
    const float* W2    = (const float*)d_in[11];
    const float* b2    = (const float*)d_in[12];
    float* out = (float*)d_out;

    // workspace: xb bf16[256*512*64] @0 (16 MB); h0sq bf16[256*512*128] @16 MB (32 MB); flags @48 MB
    char* ws = (char*)d_ws;
    unsigned short* xb    = (unsigned short*)ws;
    unsigned short* h0sq  = (unsigned short*)(ws + 16777216);
    int*            flags = (int*)(ws + 50331648);

    conv_x_kernel<<<8192, 256, 0, stream>>>(x, xb, (BATCH * SEQ * INDIM) / 4, flags);
    lstm_fused_kernel<<<2 * NTILE, 256, 0, stream>>>(xb, W_ih0, W_hh0, b_ih0, b_hh0,
                                                     W_ih1, W_hh1, b_ih1, b_hh1,
                                                     h0sq, W1, b1, W2, b2, out, flags);
}